// Round 4
// baseline (300.333 us; speedup 1.0000x reference)
//
#include <hip/hip_runtime.h>

// MultinomialDiffusion.q_posterior — V5: async DMA staging (global_load_lds),
// per-stream bursts, counted-vmcnt software pipeline.
//
// Evidence: V1-V4 (register loads; NT vs normal stores; 16/28 VGPR; 52-72%
// occupancy; persistent and non-persistent) ALL land at 2.4-2.55 TB/s HBM,
// exactly half the m13 copy's per-CU rate (5 vs 10 B/cyc/CU). Read side =
// 2.5 B/cyc/CU ~= 32 lines x 64B / ~800cyc loaded latency -> consistent with
// a per-CU outstanding-miss cap; more register-load MLP (V2) queues at the CU
// and does nothing. Levers under that model: (1) the DMA path (no VGPR dest,
// direct TA->L2->LDS), (2) lower loaded latency via long per-stream DRAM
// bursts (8KB/stream/block back-to-back instead of 1KB 4-stream interleave).
//
// Structure: 1024 blocks (64/batch, all co-resident; LDS 32KB -> 5 blocks/CU
// capacity). Block window = 64KB/stream, split into 8 tiles of 8KB. Each wave
// stages ITS OWN 2KB slice of each tile via 2+2 global_load_lds_dwordx4
// (xt burst then x0 burst), double-buffered; consumes it via ds_read_b128.
// No barriers (wave-private slices). vmcnt discipline per wave per tile:
//   issue L_{t+1} (4 DMA) ; s_waitcnt vmcnt(8) guarantees L_t done
//   (8 = S_{t-1} 4 stores + L_{t+1} 4 loads, the only ops younger than L_t;
//   vmcnt retires in issue order). Peeled first/last iterations use vmcnt(4).
// Stores burst out0 (2KB) then out1 (2KB) straight from registers.

#define LL (1024 * 1024)
#define BLOCKS_PER_B 64
#define TILES 8
#define TILE_E 2048                  // elems per tile per block = 8 KB/stream
#define GRID (16 * BLOCKS_PER_B)     // 1024 blocks

typedef float vfloat4 __attribute__((ext_vector_type(4)));
typedef const __attribute__((address_space(1))) void cgv_t;  // global (as1)
typedef __attribute__((address_space(3))) void lsv_t;        // LDS (as3)

__global__ __launch_bounds__(256) void qposterior_kernel(
    const float* __restrict__ lxt,
    const float* __restrict__ lx0,
    const float* __restrict__ la,
    const float* __restrict__ l1a,
    const float* __restrict__ lab,
    const float* __restrict__ l1ab,
    const int* __restrict__ tarr,
    float* __restrict__ out)
{
    __shared__ float lds_xt[2][TILE_E];   // 2 x 8 KB
    __shared__ float lds_x0[2][TILE_E];   // 2 x 8 KB   -> 32 KB total

    const float LOGK = 0.6931471805599453f; // log(2)

    int bid   = blockIdx.x;
    int b     = bid >> 6;                 // 64 blocks per batch
    int local = bid & (BLOCKS_PER_B - 1);
    int tid   = threadIdx.x;
    int w     = tid >> 6;                 // wave 0..3
    int lane  = tid & 63;

    // ---- per-batch scalars (wave-uniform) ----
    int tb_ = tarr[b];
    bool t0 = (tb_ == 0);
    float C = la[tb_];
    float D = l1a[tb_] - LOGK;
    float mm = fmaxf(C, D);
    float s_hot = mm + __logf(1.0f + __expf(fminf(C, D) - mm));
    float delta = s_hot - D;              // logaddexp(C,D) - D

    float a = 0.f, c = 0.f, apc = 0.f;
    if (!t0) {
        int tm1 = tb_ - 1;
        a   = __expf(lab[tm1]);           // alpha_bar[t-1]
        c   = 0.5f * __expf(l1ab[tm1]);   // (1 - alpha_bar[t-1]) / 2
        apc = a + c;
    }

    const float* xt_p  = lxt + b * (2 * LL);
    const float* x0_p  = lx0 + b * (2 * LL);
    float*       out_p = out + b * (2 * LL);

    int blk_base = local * (TILES * TILE_E);  // 16384 elems per block window
    int wbase    = w * 512;                   // wave's 512-elem slice of a tile

    if (!t0) {
        // ---- async DMA stage of one tile slice (4 x 16B/lane, vmcnt-counted) ----
        auto stage = [&](int buf, int t) {
            int gb = blk_base + t * TILE_E + wbase + lane * 4;
            // xt burst (2 KB contiguous per wave, 8 KB per block)
            __builtin_amdgcn_global_load_lds((cgv_t*)(xt_p + gb),
                                             (lsv_t*)&lds_xt[buf][wbase],       16, 0, 0);
            __builtin_amdgcn_global_load_lds((cgv_t*)(xt_p + gb + 256),
                                             (lsv_t*)&lds_xt[buf][wbase + 256], 16, 0, 0);
            // x0 burst
            __builtin_amdgcn_global_load_lds((cgv_t*)(x0_p + gb),
                                             (lsv_t*)&lds_x0[buf][wbase],       16, 0, 0);
            __builtin_amdgcn_global_load_lds((cgv_t*)(x0_p + gb + 256),
                                             (lsv_t*)&lds_x0[buf][wbase + 256], 16, 0, 0);
        };

        auto compute_store = [&](int buf, int t) {
            int gb = blk_base + t * TILE_E + wbase + lane * 4;
            vfloat4 r0[2], r1[2];
#pragma unroll
            for (int i = 0; i < 2; ++i) {
                vfloat4 xt4 = *(vfloat4*)&lds_xt[buf][wbase + i * 256 + lane * 4];
                vfloat4 x04 = *(vfloat4*)&lds_x0[buf][wbase + i * 256 + lane * 4];
#pragma unroll
                for (int j = 0; j < 4; ++j) {
                    float p  = __expf(x04[j]);
                    float e0 = __logf(fmaf(a, p, c));
                    float e1 = __logf(fmaf(-a, p, apc));
                    float d  = e0 - e1;
                    float sd    = (xt4[j] > -35.0f) ? delta : -delta;
                    float Delta = d + sd;
                    // o0 = -logaddexp(0, -Delta)
                    float m  = fmaxf(-Delta, 0.0f);
                    float o0 = -(m + __logf(1.0f + __expf(-fabsf(Delta))));
                    r0[i][j] = o0;
                    r1[i][j] = o0 - Delta;
                }
            }
            // store bursts: out0 run, then out1 run
            *(vfloat4*)(out_p + gb)            = r0[0];
            *(vfloat4*)(out_p + gb + 256)      = r0[1];
            *(vfloat4*)(out_p + gb + LL)       = r1[0];
            *(vfloat4*)(out_p + gb + LL + 256) = r1[1];
        };

        // ---- software pipeline (peeled ends for exact vmcnt counts) ----
        stage(0, 0);
        stage(1, 1);
        // guarantee L0 done: ops younger than L0 = L1 (4)
        asm volatile("s_waitcnt vmcnt(4)" ::: "memory");
        __builtin_amdgcn_sched_barrier(0);
        compute_store(0, 0);

#pragma unroll
        for (int t = 1; t < TILES - 1; ++t) {
            stage((t + 1) & 1, t + 1);
            // younger than L_t: S_{t-1} (4) + L_{t+1} (4) = 8
            asm volatile("s_waitcnt vmcnt(8)" ::: "memory");
            __builtin_amdgcn_sched_barrier(0);
            compute_store(t & 1, t);
        }

        // last tile: younger than L_{TILES-1} = S_{TILES-2} (4)
        asm volatile("s_waitcnt vmcnt(4)" ::: "memory");
        __builtin_amdgcn_sched_barrier(0);
        compute_store((TILES - 1) & 1, TILES - 1);
    } else {
        // ================= t == 0 path (rare; uniform per batch) =================
        // d = log_x_0[class0] - log_x_0[class1]; plain register loads.
        for (int t = 0; t < TILES; ++t) {
#pragma unroll
            for (int j = 0; j < 2; ++j) {
                int e = blk_base + t * TILE_E + (j * 256 + tid) * 4;
                vfloat4 xt = *(const vfloat4*)(xt_p + e);
                vfloat4 x0 = *(const vfloat4*)(x0_p + e);
                vfloat4 x1 = *(const vfloat4*)(x0_p + e + LL);
                vfloat4 r0, r1;
#pragma unroll
                for (int i = 0; i < 4; ++i) {
                    float d = x0[i] - x1[i];
                    float sd    = (xt[i] > -35.0f) ? delta : -delta;
                    float Delta = d + sd;
                    float m  = fmaxf(-Delta, 0.0f);
                    float o0 = -(m + __logf(1.0f + __expf(-fabsf(Delta))));
                    r0[i] = o0;
                    r1[i] = o0 - Delta;
                }
                *(vfloat4*)(out_p + e)      = r0;
                *(vfloat4*)(out_p + e + LL) = r1;
            }
        }
    }
}

extern "C" void kernel_launch(void* const* d_in, const int* in_sizes, int n_in,
                              void* d_out, int out_size, void* d_ws, size_t ws_size,
                              hipStream_t stream) {
    const float* lxt  = (const float*)d_in[0];
    const float* lx0  = (const float*)d_in[1];
    const float* la   = (const float*)d_in[2];
    const float* l1a  = (const float*)d_in[3];
    const float* lab  = (const float*)d_in[4];
    const float* l1ab = (const float*)d_in[5];
    const int*   tarr = (const int*)d_in[6];
    float*       out  = (float*)d_out;

    qposterior_kernel<<<GRID, 256, 0, stream>>>(lxt, lx0, la, l1a, lab, l1ab, tarr, out);
}

// Round 5
// 293.568 us; speedup vs baseline: 1.0230x; 1.0230x over previous
//
#include <hip/hip_runtime.h>

// MultinomialDiffusion.q_posterior — V6: FLAT GRID-STRIDE CONVOY (copy-shaped).
//
// Ledger: V1 (block windows, NT stores)=82us; V2 (+8-deep load hoist)=81;
// V3 (normal stores, contiguous 16KB windows)=79; V4 (persistent pipelined)=84;
// V5 (global_load_lds DMA, counted vmcnt)=89. ALL pinned at 2.3-2.55 TB/s HBM
// while fillBuffer=6.8 and float4-copy=6.3 TB/s on the same chip. Per-wave
// in-flight depth (2KB..8KB), store policy, and load path were all varied and
// did nothing -> the limiter is none of them.
//
// The one thing never varied: INSTANTANEOUS GLOBAL FOOTPRINT. All previous
// versions gave each block a private window, so ~2000 resident blocks touch
// ~2000 scattered shards x 4 streams at once; each HBM channel services a
// near-random 64B request mix -> every read a DRAM page miss -> read BW
// pinned at inflight/latency ~2.5 B/cyc/CU. The 85%-of-peak kernels (fill,
// copy) are flat grid-stride convoys: the whole GPU marches through ONE
// contiguous window per stream (8MB/step here), giving each channel long
// same-page runs. V6 reshapes the kernel into exactly that.
//
// Also: algebraic simplification. With u = a*p+c, v = a*(1-p)+c, F = e^{sd}:
//   o0 = log u + sd - log(u*F + v),   o1 = log v - log(u*F + v)
// (4 transcendentals/elem instead of 5, branch-free hot math).

#define LL (1024 * 1024)
#define GROUPS_PER_PLANE (1 << 18)     // float4 groups per 1024x1024 plane
#define NBLOCKS 2048                   // 8 blocks/CU, all co-resident
#define NTHREADS 256
#define GSTRIDE (NBLOCKS * NTHREADS)   // 524288 groups = 8MB/stream per sweep
#define NITER ((16 * GROUPS_PER_PLANE) / GSTRIDE)   // = 8, exact, no tail

typedef float vfloat4 __attribute__((ext_vector_type(4)));

__global__ __launch_bounds__(256) void qposterior_kernel(
    const float* __restrict__ lxt,
    const float* __restrict__ lx0,
    const float* __restrict__ la,
    const float* __restrict__ l1a,
    const float* __restrict__ lab,
    const float* __restrict__ l1ab,
    const int* __restrict__ tarr,
    float* __restrict__ out)
{
    const float LOGK = 0.6931471805599453f; // log(2)

    int g = blockIdx.x * NTHREADS + threadIdx.x;   // flat float4-group id

#pragma unroll 2
    for (int it = 0; it < NITER; ++it, g += GSTRIDE) {
        int b  = g >> 18;                          // batch (wave-uniform)
        int eg = (g & (GROUPS_PER_PLANE - 1)) << 2; // element offset in plane

        const float* xt_p  = lxt + b * (2 * LL) + eg;
        const float* x0_p  = lx0 + b * (2 * LL) + eg;
        float*       out_p = out + b * (2 * LL) + eg;

        // Issue the two stream loads first; scalar setup overlaps the latency.
        vfloat4 xt4 = *reinterpret_cast<const vfloat4*>(xt_p);
        vfloat4 x04 = *reinterpret_cast<const vfloat4*>(x0_p);

        // ---- per-batch scalars (wave-uniform, tables are L1-resident) ----
        int tb = tarr[b];
        float C = la[tb];
        float D = l1a[tb] - LOGK;
        float mm = fmaxf(C, D);
        float s_hot = mm + __logf(1.0f + __expf(fminf(C, D) - mm));
        float delta = s_hot - D;                   // logaddexp(C,D) - D  (>= 0)

        vfloat4 r0, r1;
        if (tb != 0) {
            int tm1 = tb - 1;
            float a   = __expf(lab[tm1]);          // alpha_bar[t-1]
            float c   = 0.5f * __expf(l1ab[tm1]);  // (1 - alpha_bar[t-1]) / 2
            float apc = a + c;
            float Fp  = __expf(delta);
            float Fm  = __expf(-delta);
#pragma unroll
            for (int i = 0; i < 4; ++i) {
                float p  = __expf(x04[i]);
                float u  = fmaf(a, p, c);          // a*p + c
                float v  = fmaf(-a, p, apc);       // a*(1-p) + c
                bool hot = (xt4[i] > -35.0f);
                float F  = hot ? Fp : Fm;
                float sd = hot ? delta : -delta;
                float w  = fmaf(u, F, v);          // u*e^{sd} + v
                float lu = __logf(u);
                float lv = __logf(v);
                float lw = __logf(w);
                r0[i] = (lu - lw) + sd;            // o0
                r1[i] = lv - lw;                   // o1
            }
        } else {
            // t == 0 (rare, wave-uniform): d = l00 - l01, stable direct form.
            vfloat4 x14 = *reinterpret_cast<const vfloat4*>(x0_p + LL);
#pragma unroll
            for (int i = 0; i < 4; ++i) {
                float d     = x04[i] - x14[i];
                float sd    = (xt4[i] > -35.0f) ? delta : -delta;
                float Delta = d + sd;
                float m  = fmaxf(-Delta, 0.0f);
                float o0 = -(m + __logf(1.0f + __expf(-fabsf(Delta))));
                r0[i] = o0;
                r1[i] = o0 - Delta;
            }
        }

        *reinterpret_cast<vfloat4*>(out_p)      = r0;
        *reinterpret_cast<vfloat4*>(out_p + LL) = r1;
    }
}

extern "C" void kernel_launch(void* const* d_in, const int* in_sizes, int n_in,
                              void* d_out, int out_size, void* d_ws, size_t ws_size,
                              hipStream_t stream) {
    const float* lxt  = (const float*)d_in[0];
    const float* lx0  = (const float*)d_in[1];
    const float* la   = (const float*)d_in[2];
    const float* l1a  = (const float*)d_in[3];
    const float* lab  = (const float*)d_in[4];
    const float* l1ab = (const float*)d_in[5];
    const int*   tarr = (const int*)d_in[6];
    float*       out  = (float*)d_out;

    qposterior_kernel<<<NBLOCKS, NTHREADS, 0, stream>>>(lxt, lx0, la, l1a, lab, l1ab, tarr, out);
}

// Round 7
// 289.045 us; speedup vs baseline: 1.0391x; 1.0157x over previous
//
#include <hip/hip_runtime.h>

// MultinomialDiffusion.q_posterior — V7b: TWO-KERNEL SPLIT (traffic-mix probe).
// (Resubmission of V7 — round 6 failed on container acquisition, kernel never ran.)
//
// Ledger: V1 82us (NT stores), V2 81 (8-deep hoist), V3 79 (WB stores),
// V4 84 (persistent pipeline), V5 89 (global_load_lds DMA), V6 82 (flat
// convoy, 4 transc/elem) — ALL at 2.4-2.55 TB/s HBM-side, while on the same
// chip: fill (1 stream) = 6.8 TB/s, float4-copy (2 streams) = 6.3 TB/s.
// Per-wave MLP, store policy, load path, occupancy, and global footprint are
// all refuted levers. The untested invariant is the per-dispatch traffic MIX:
// every version issues 4 fat interleaved streams per wave. V7 splits:
//   K1: xt plane0 (64MB) -> 2MB hot-bitmask in workspace  [read-dominant]
//   K2: x0 plane0 (64MB) + mask (2MB, L2-hot) -> out0+out1 (128MB) [write 2:1]
// xt is log-one-hot (1 useful bit/elem) so the mask is lossless; also cuts
// fat-stream bytes 192MB -> ~130MB across the pair.
// Decision rule: if K1 AND K2 both pin at ~2.45 TB/s despite opposite R:W
// mixes, the plateau is structural -> revert fused, declare roofline.

#define LL (1024 * 1024)
#define BPB 512                  // blocks per batch: 512 x 256thr x 8elem = 2^20
#define NBLK (16 * BPB)          // 8192 blocks
#define MASK_BYTES (NBLK * 256)  // 2 MB, one byte per thread (8 elems)

typedef float vfloat4 __attribute__((ext_vector_type(4)));

__device__ __forceinline__ int mask_idx(int bid, int tid) { return (bid << 8) | tid; }

// ---------------- K1: hot-bit mask from log-one-hot xt ----------------
__global__ __launch_bounds__(256) void mask_kernel(
    const float* __restrict__ lxt, unsigned char* __restrict__ mask)
{
    int bid   = blockIdx.x;
    int b     = bid >> 9;
    int local = bid & (BPB - 1);
    int e0    = local * 2048 + threadIdx.x * 4;   // block window: 8KB contiguous

    const float* xt_p = lxt + b * (2 * LL);
    vfloat4 xa = *reinterpret_cast<const vfloat4*>(xt_p + e0);
    vfloat4 xb = *reinterpret_cast<const vfloat4*>(xt_p + e0 + 1024);

    unsigned int m = 0;
#pragma unroll
    for (int j = 0; j < 4; ++j) m |= (xa[j] > -35.0f ? 1u : 0u) << j;
#pragma unroll
    for (int j = 0; j < 4; ++j) m |= (xb[j] > -35.0f ? 1u : 0u) << (4 + j);

    mask[mask_idx(bid, threadIdx.x)] = (unsigned char)m;
}

// ---------------- K2: posterior from x0 + mask ----------------
__global__ __launch_bounds__(256) void qpost_kernel(
    const float* __restrict__ lx0,
    const unsigned char* __restrict__ mask,
    const float* __restrict__ la,
    const float* __restrict__ l1a,
    const float* __restrict__ lab,
    const float* __restrict__ l1ab,
    const int* __restrict__ tarr,
    float* __restrict__ out)
{
    const float LOGK = 0.6931471805599453f; // log(2)

    int bid   = blockIdx.x;
    int b     = bid >> 9;
    int local = bid & (BPB - 1);
    int e0    = local * 2048 + threadIdx.x * 4;

    const float* x0_p  = lx0 + b * (2 * LL);
    float*       out_p = out + b * (2 * LL);

    // issue fat loads first
    vfloat4 A  = *reinterpret_cast<const vfloat4*>(x0_p + e0);
    vfloat4 Bv = *reinterpret_cast<const vfloat4*>(x0_p + e0 + 1024);
    unsigned int m = mask[mask_idx(bid, threadIdx.x)];

    // ---- per-batch scalars (wave-uniform) ----
    int tb = tarr[b];
    float C = la[tb];
    float D = l1a[tb] - LOGK;
    float mm = fmaxf(C, D);
    float s_hot = mm + __logf(1.0f + __expf(fminf(C, D) - mm));
    float delta = s_hot - D;              // logaddexp(C,D) - D  (>= 0)

    vfloat4 r0a, r1a, r0b, r1b;
    if (tb != 0) {
        int tm1 = tb - 1;
        float a   = __expf(lab[tm1]);          // alpha_bar[t-1]
        float c   = 0.5f * __expf(l1ab[tm1]);  // (1 - alpha_bar[t-1]) / 2
        float apc = a + c;
        float Fp  = __expf(delta);
        float Fm  = __expf(-delta);
#pragma unroll
        for (int i = 0; i < 4; ++i) {
            float p  = __expf(A[i]);
            float u  = fmaf(a, p, c);
            float v  = fmaf(-a, p, apc);
            bool hot = (m >> i) & 1u;
            float F  = hot ? Fp : Fm;
            float sd = hot ? delta : -delta;
            float w  = fmaf(u, F, v);
            float lw = __logf(w);
            r0a[i] = (__logf(u) - lw) + sd;
            r1a[i] = __logf(v) - lw;
        }
#pragma unroll
        for (int i = 0; i < 4; ++i) {
            float p  = __expf(Bv[i]);
            float u  = fmaf(a, p, c);
            float v  = fmaf(-a, p, apc);
            bool hot = (m >> (4 + i)) & 1u;
            float F  = hot ? Fp : Fm;
            float sd = hot ? delta : -delta;
            float w  = fmaf(u, F, v);
            float lw = __logf(w);
            r0b[i] = (__logf(u) - lw) + sd;
            r1b[i] = __logf(v) - lw;
        }
    } else {
        // t == 0 (rare, wave-uniform): d = l00 - l01 needs plane-1 of x0.
        vfloat4 x1a = *reinterpret_cast<const vfloat4*>(x0_p + e0 + LL);
        vfloat4 x1b = *reinterpret_cast<const vfloat4*>(x0_p + e0 + 1024 + LL);
#pragma unroll
        for (int i = 0; i < 4; ++i) {
            float d     = A[i] - x1a[i];
            float sd    = ((m >> i) & 1u) ? delta : -delta;
            float Delta = d + sd;
            float mo = fmaxf(-Delta, 0.0f);
            float o0 = -(mo + __logf(1.0f + __expf(-fabsf(Delta))));
            r0a[i] = o0;
            r1a[i] = o0 - Delta;
        }
#pragma unroll
        for (int i = 0; i < 4; ++i) {
            float d     = Bv[i] - x1b[i];
            float sd    = ((m >> (4 + i)) & 1u) ? delta : -delta;
            float Delta = d + sd;
            float mo = fmaxf(-Delta, 0.0f);
            float o0 = -(mo + __logf(1.0f + __expf(-fabsf(Delta))));
            r0b[i] = o0;
            r1b[i] = o0 - Delta;
        }
    }

    // stream-grouped stores: 2KB run on out plane0, then 2KB run on plane1
    *reinterpret_cast<vfloat4*>(out_p + e0)              = r0a;
    *reinterpret_cast<vfloat4*>(out_p + e0 + 1024)       = r0b;
    *reinterpret_cast<vfloat4*>(out_p + e0 + LL)         = r1a;
    *reinterpret_cast<vfloat4*>(out_p + e0 + 1024 + LL)  = r1b;
}

// ---------------- fallback: fused single kernel (V6) ----------------
#define GROUPS_PER_PLANE (1 << 18)
#define FB_NBLOCKS 2048
#define FB_GSTRIDE (FB_NBLOCKS * 256)
#define FB_NITER ((16 * GROUPS_PER_PLANE) / FB_GSTRIDE)

__global__ __launch_bounds__(256) void qposterior_fused(
    const float* __restrict__ lxt,
    const float* __restrict__ lx0,
    const float* __restrict__ la,
    const float* __restrict__ l1a,
    const float* __restrict__ lab,
    const float* __restrict__ l1ab,
    const int* __restrict__ tarr,
    float* __restrict__ out)
{
    const float LOGK = 0.6931471805599453f;
    int g = blockIdx.x * 256 + threadIdx.x;
#pragma unroll 2
    for (int it = 0; it < FB_NITER; ++it, g += FB_GSTRIDE) {
        int b  = g >> 18;
        int eg = (g & (GROUPS_PER_PLANE - 1)) << 2;
        const float* xt_p  = lxt + b * (2 * LL) + eg;
        const float* x0_p  = lx0 + b * (2 * LL) + eg;
        float*       out_p = out + b * (2 * LL) + eg;
        vfloat4 xt4 = *reinterpret_cast<const vfloat4*>(xt_p);
        vfloat4 x04 = *reinterpret_cast<const vfloat4*>(x0_p);
        int tb = tarr[b];
        float C = la[tb];
        float D = l1a[tb] - LOGK;
        float mm = fmaxf(C, D);
        float s_hot = mm + __logf(1.0f + __expf(fminf(C, D) - mm));
        float delta = s_hot - D;
        vfloat4 r0, r1;
        if (tb != 0) {
            int tm1 = tb - 1;
            float a   = __expf(lab[tm1]);
            float c   = 0.5f * __expf(l1ab[tm1]);
            float apc = a + c;
            float Fp  = __expf(delta);
            float Fm  = __expf(-delta);
#pragma unroll
            for (int i = 0; i < 4; ++i) {
                float p  = __expf(x04[i]);
                float u  = fmaf(a, p, c);
                float v  = fmaf(-a, p, apc);
                bool hot = (xt4[i] > -35.0f);
                float F  = hot ? Fp : Fm;
                float sd = hot ? delta : -delta;
                float w  = fmaf(u, F, v);
                float lw = __logf(w);
                r0[i] = (__logf(u) - lw) + sd;
                r1[i] = __logf(v) - lw;
            }
        } else {
            vfloat4 x14 = *reinterpret_cast<const vfloat4*>(x0_p + LL);
#pragma unroll
            for (int i = 0; i < 4; ++i) {
                float d     = x04[i] - x14[i];
                float sd    = (xt4[i] > -35.0f) ? delta : -delta;
                float Delta = d + sd;
                float mo = fmaxf(-Delta, 0.0f);
                float o0 = -(mo + __logf(1.0f + __expf(-fabsf(Delta))));
                r0[i] = o0;
                r1[i] = o0 - Delta;
            }
        }
        *reinterpret_cast<vfloat4*>(out_p)      = r0;
        *reinterpret_cast<vfloat4*>(out_p + LL) = r1;
    }
}

extern "C" void kernel_launch(void* const* d_in, const int* in_sizes, int n_in,
                              void* d_out, int out_size, void* d_ws, size_t ws_size,
                              hipStream_t stream) {
    const float* lxt  = (const float*)d_in[0];
    const float* lx0  = (const float*)d_in[1];
    const float* la   = (const float*)d_in[2];
    const float* l1a  = (const float*)d_in[3];
    const float* lab  = (const float*)d_in[4];
    const float* l1ab = (const float*)d_in[5];
    const int*   tarr = (const int*)d_in[6];
    float*       out  = (float*)d_out;

    if (d_ws != nullptr && ws_size >= (size_t)MASK_BYTES) {
        unsigned char* mask = (unsigned char*)d_ws;
        mask_kernel<<<NBLK, 256, 0, stream>>>(lxt, mask);
        qpost_kernel<<<NBLK, 256, 0, stream>>>(lx0, mask, la, l1a, lab, l1ab, tarr, out);
    } else {
        qposterior_fused<<<FB_NBLOCKS, 256, 0, stream>>>(lxt, lx0, la, l1a, lab, l1ab, tarr, out);
    }
}